// Round 6
// baseline (92.685 us; speedup 1.0000x reference)
//
#include <hip/hip_runtime.h>
#include <math.h>

#define IR_LEN  2000
#define PFRAME  80
#define NFRAMES 300
#define NBATCH  2
#define NROWS   (NBATCH*NFRAMES)     // 600
#define T_TOTAL (NFRAMES*PFRAME)     // 24000
#define NCOEF   25
#define TWO_PI  6.283185307179586f
#define GS      68                   // G row stride in floats
#define XWN     2160                 // logical x-window floats per block
#define XWPAD   2432                 // physical (4-float pad per 32)

#define XPHYS(B) ((B) + (((B) >> 5) << 2))

__device__ __forceinline__ void fsincos(float a, float* s, float* c) {
    *s = __sinf(a); *c = __cosf(a);
}

// ---------------------------------------------------------------------------
// R22 = R21 resubmit (previous round was an infra failure; never measured).
// Structural two-kernel split of R17 (proven 41 us fused / 87.3 bench).
// R17/R19/R20 post-mortems: -20% VALU -> flat; 2x waves -> worse; prefetch ->
// flat. The invariant is the grid: 600 blocks / 256 CUs = 2.3 blocks/CU,
// all pipes <40% busy -> bound by per-block critical path with too few
// blocks to overlap. Split at the h seam:
//   A (600 blocks): E + S1 + S2 (verbatim), h written register->global hw.
//     No x-stage / FIR / epilogue. Also: rocprof now times A and B
//     separately = the per-phase ablation we've been missing.
//   B (1200 blocks = row x half): stages x-window + h, FIR for 80 outputs
//     re-chunked 25 chunks x 80 taps x 20 iters (no tail), tent-weighted
//     atomic scatter. Per-thread serial FIR work halves; block concurrency
//     doubles on the FIR half of the work.
// ---------------------------------------------------------------------------

// ======================= kernel A: h = minphase(mc) ========================
__global__ __launch_bounds__(256) void minphase_h(
        const float* __restrict__ mc, float* __restrict__ hw) {
    __shared__ __align__(16) float U[8192];    // 32.8 KB union (E / G)
    __shared__ float csh[NCOEF];
    float* const EHr = U;                      // [4096]      (phase E)
    float* const EHi = U + 4096;               // [4096]
    float* const Gr  = U;                      // [rows b<=32] (stages 1/2)
    float* const Gi  = U + 4352;               // [rows b<=32]

    const int row   = blockIdx.x;
    const int t     = threadIdx.x;

    if (t < NCOEF) csh[t] = mc[row * NCOEF + t];
    __syncthreads();

    // ---------------- phase E (Clenshaw, conjugate mirror, chained base) --
    {
        float creg[NCOEF];
        #pragma unroll
        for (int k = 0; k < NCOEF; k++) creg[k] = csh[k];

        float bs, bc; fsincos(-(TWO_PI / 4096.0f) * (float)t, &bs, &bc);
        const float SC =  0.923879532511287f;   // cos(pi/8)
        const float SS = -0.382683432365090f;   // sin(-pi/8)
        #pragma unroll 4
        for (int ii = 0; ii < 8; ii++) {
            const int f = t + 256 * ii;                // 0..2047
            const float wc = bc, ws = bs;              // e^{-2pi i f/4096}
            { const float nr = bc * SC - bs * SS;      // advance base
              const float ni = bc * SS + bs * SC;
              bc = nr; bs = ni; }
            const float t2 = 2.0f * wc;
            float b1 = 0.0f, b2 = 0.0f;
            #pragma unroll
            for (int k = NCOEF - 1; k >= 1; k--) {
                const float bk = __fmaf_rn(t2, b1, creg[k] - b2);
                b2 = b1; b1 = bk;
            }
            const float Cr = __fmaf_rn(wc, b1, creg[0] - b2);
            const float Ci = ws * b1;
            const float m = __expf(Cr);
            float si, co; fsincos(Ci, &si, &co);
            const float er = m * co, ei = m * si;
            EHr[f] = er; EHi[f] = ei;
            if (f > 0) { EHr[4096 - f] = er; EHi[4096 - f] = -ei; }
        }
        if (t == 0) {                                  // f = 2048
            float Cr = 0.0f, Ci = 0.0f;
            float cr = 1.0f, ci = 0.0f;
            #pragma unroll
            for (int k = 0; k < NCOEF; k++) {
                Cr += csh[k] * cr; Ci += csh[k] * ci;
                cr = -cr; ci = -ci;                    // e^{-i pi k} = (-1)^k
            }
            const float m = __expf(Cr);
            float si, co; fsincos(Ci, &si, &co);
            EHr[2048] = m * co; EHi[2048] = m * si;
        }
    }
    __syncthreads();

    // ------- stage 1 (R16 shape, wave-contiguous Hermitian tiles) ---------
    {
        const bool act = t < 144;              // waves 0-1 dense, w2 1/4, w3 off
        const int bg = t % 9;                  // b-group 0..8  (b0 = 0..32)
        const int dp = t / 9;                  // d-pair 0..15  (for t < 144)
        const int b0 = bg * 4;
        const int d0 = dp * 2;
        float Ter[2][4], Tei[2][4], Tor[2][4], Toi[2][4];
        #pragma unroll
        for (int j = 0; j < 2; j++)
            #pragma unroll
            for (int i = 0; i < 4; i++) {
                Ter[j][i] = 0.0f; Tei[j][i] = 0.0f;
                Tor[j][i] = 0.0f; Toi[j][i] = 0.0f;
            }
        float rr[2], ri[2], wr[2], wi[2];
        if (act) {
            #pragma unroll
            for (int j = 0; j < 2; j++) {
                float s, c; fsincos((TWO_PI / 32.0f) * (float)(d0 + j), &s, &c);
                wr[j] = c; wi[j] = s; rr[j] = 1.0f; ri[j] = 0.0f;
            }
            float4 vre = *(const float4*)&EHr[b0];
            float4 vie = *(const float4*)&EHi[b0];
            float4 vro = *(const float4*)&EHr[64 + b0];
            float4 vio = *(const float4*)&EHi[64 + b0];
            #pragma unroll 4
            for (int a2 = 0; a2 < 32; a2++) {
                const float4 cre = vre, cie = vie, cro = vro, cio = vio;
                if (a2 < 31) {
                    const int nb = 128 * (a2 + 1) + b0;
                    vre = *(const float4*)&EHr[nb];
                    vie = *(const float4*)&EHi[nb];
                    vro = *(const float4*)&EHr[nb + 64];
                    vio = *(const float4*)&EHi[nb + 64];
                }
                const float ere[4] = {cre.x, cre.y, cre.z, cre.w};
                const float eie[4] = {cie.x, cie.y, cie.z, cie.w};
                const float ero[4] = {cro.x, cro.y, cro.z, cro.w};
                const float eio[4] = {cio.x, cio.y, cio.z, cio.w};
                #pragma unroll
                for (int j = 0; j < 2; j++) {
                    #pragma unroll
                    for (int i = 0; i < 4; i++) {
                        Ter[j][i] += ere[i] * rr[j] - eie[i] * ri[j];
                        Tei[j][i] += ere[i] * ri[j] + eie[i] * rr[j];
                        Tor[j][i] += ero[i] * rr[j] - eio[i] * ri[j];
                        Toi[j][i] += ero[i] * ri[j] + eio[i] * rr[j];
                    }
                    const float nr = rr[j] * wr[j] - ri[j] * wi[j];
                    const float ni = rr[j] * wi[j] + ri[j] * wr[j];
                    rr[j] = nr; ri[j] = ni;
                }
            }
        }
        __syncthreads();   // uniform barrier: ALL E reads done before G' store

        if (act) {
            float os[2], oc[2];
            #pragma unroll
            for (int j = 0; j < 2; j++)
                fsincos((TWO_PI / 64.0f) * (float)(d0 + j), &os[j], &oc[j]);
            #pragma unroll
            for (int i = 0; i < 4; i++) {
                const int b = b0 + i;
                if (b > 32) continue;
                float gpr[2], gpi[2], gmr[2], gmi[2];
                #pragma unroll
                for (int j = 0; j < 2; j++) {
                    const int d = d0 + j;
                    const float ur = oc[j] * Tor[j][i] - os[j] * Toi[j][i];
                    const float ui = oc[j] * Toi[j][i] + os[j] * Tor[j][i];
                    const float pr = Ter[j][i] + ur, pi = Tei[j][i] + ui;
                    const float mr = Ter[j][i] - ur, mi = Tei[j][i] - ui;
                    float s, c;
                    fsincos((TWO_PI / 4096.0f) * (float)(b * d), &s, &c);
                    gpr[j] = pr * c - pi * s; gpi[j] = pr * s + pi * c;
                    fsincos((TWO_PI / 4096.0f) * (float)(b * (d + 32)), &s, &c);
                    gmr[j] = mr * c - mi * s; gmi[j] = mr * s + mi * c;
                }
                *(float2*)&Gr[b * GS + d0]      = make_float2(gpr[0], gpr[1]);
                *(float2*)&Gi[b * GS + d0]      = make_float2(gpi[0], gpi[1]);
                *(float2*)&Gr[b * GS + d0 + 32] = make_float2(gmr[0], gmr[1]);
                *(float2*)&Gi[b * GS + d0 + 32] = make_float2(gmi[0], gmi[1]);
            }
        }
    }
    __syncthreads();

    // ---------------- stage 2 (R17 rolled loop, 4 groups = b 0..31) -------
    {
        const int dl = (t & 31) * 2;
        const int cg = t >> 5;                     // 0..7
        float swi_, swr_; fsincos((TWO_PI / 64.0f) * (float)cg, &swi_, &swr_);
        const float swr = swr_, swi = swi_;        // step e^{2pi i cg/64}
        float rr = 1.0f, ri = 0.0f;
        float acc00 = 0, acc01 = 0, acc10 = 0, acc11 = 0;
        float acc20 = 0, acc21 = 0, acc30 = 0, acc31 = 0;
        int bb = 0;

#define S2C 0.70710678118654752f
#define STEP2(f8r, f8i, f16r, f16i, f24r, f24i)                                \
        {                                                                      \
            const float2 g_r = *(const float2*)&Gr[bb * GS + dl];              \
            const float2 g_i = *(const float2*)&Gi[bb * GS + dl];              \
            acc00 += g_r.x * rr - g_i.x * ri;                                  \
            acc01 += g_r.y * rr - g_i.y * ri;                                  \
            { const float tr = rr*(f8r) - ri*(f8i), ti = rr*(f8i) + ri*(f8r);  \
              acc10 += g_r.x * tr - g_i.x * ti;                                \
              acc11 += g_r.y * tr - g_i.y * ti; }                              \
            { const float tr = rr*(f16r) - ri*(f16i), ti = rr*(f16i) + ri*(f16r); \
              acc20 += g_r.x * tr - g_i.x * ti;                                \
              acc21 += g_r.y * tr - g_i.y * ti; }                              \
            { const float tr = rr*(f24r) - ri*(f24i), ti = rr*(f24i) + ri*(f24r); \
              acc30 += g_r.x * tr - g_i.x * ti;                                \
              acc31 += g_r.y * tr - g_i.y * ti; }                              \
            { const float nr = rr * swr - ri * swi;                            \
              const float ni = rr * swi + ri * swr;                            \
              rr = nr; ri = ni; }                                              \
            bb++;                                                              \
        }

        #pragma unroll 1
        for (int grp = 0; grp < 4; grp++) {        // b = 0..31 (rolled!)
            STEP2( 1.0f, 0.0f,   1.0f, 0.0f,   1.0f, 0.0f)
            STEP2( S2C,  S2C,    0.0f, 1.0f,  -S2C,  S2C)
            STEP2( 0.0f, 1.0f,  -1.0f, 0.0f,   0.0f,-1.0f)
            STEP2(-S2C,  S2C,    0.0f,-1.0f,   S2C,  S2C)
            STEP2(-1.0f, 0.0f,   1.0f, 0.0f,  -1.0f, 0.0f)
            STEP2(-S2C, -S2C,    0.0f, 1.0f,   S2C, -S2C)
            STEP2( 0.0f,-1.0f,  -1.0f, 0.0f,   0.0f, 1.0f)
            STEP2( S2C, -S2C,    0.0f,-1.0f,  -S2C, -S2C)
        }
#undef STEP2

        // Hermitian fixup: true sum = 2*acc - g0 + (-1)^cg * g32, /4096
        const float g0a  = Gr[dl],           g0b  = Gr[dl + 1];
        const float g32a = Gr[32 * GS + dl], g32b = Gr[32 * GS + dl + 1];
        const float sgn  = (cg & 1) ? -1.0f : 1.0f;
        const float sc = 1.0f / 4096.0f;
        float hv[4][2];
        hv[0][0] = (2.0f * acc00 - g0a + sgn * g32a) * sc;
        hv[0][1] = (2.0f * acc01 - g0b + sgn * g32b) * sc;
        hv[1][0] = (2.0f * acc10 - g0a + sgn * g32a) * sc;
        hv[1][1] = (2.0f * acc11 - g0b + sgn * g32b) * sc;
        hv[2][0] = (2.0f * acc20 - g0a + sgn * g32a) * sc;
        hv[2][1] = (2.0f * acc21 - g0b + sgn * g32b) * sc;
        hv[3][0] = (2.0f * acc30 - g0a + sgn * g32a) * sc;
        hv[3][1] = (2.0f * acc31 - g0b + sgn * g32b) * sc;

        // ---- h register -> global (each half-wave writes contiguous runs)
        float* const hrow = hw + row * IR_LEN;
        #pragma unroll
        for (int v = 0; v < 4; v++) {
            const int c = cg + 8 * v;
            const int n = 64 * c + dl;             // even
            if (n + 1 < IR_LEN) {
                *(float2*)&hrow[n] = make_float2(hv[v][0], hv[v][1]);
            } else if (n < IR_LEN) {
                hrow[n] = hv[v][0];
            }
        }
    }
}

// ======================= kernel B: FIR + scatter ===========================
#define BOUT 80                      // outputs per block
#define NCH  25                      // tap chunks
#define CHL  80                      // taps per chunk (25*80 = 2000)
#define RSTR 88                      // red row stride

__global__ __launch_bounds__(256) void fir_scatter(
        const float* __restrict__ hw, const float* __restrict__ x,
        float* __restrict__ y) {
    __shared__ __align__(16) float xws[XWPAD]; // 9.7 KB padded x window
    __shared__ __align__(16) float hh[IR_LEN]; // 8 KB
    __shared__ float red[NCH * RSTR];          // 8.8 KB

    const int bid   = blockIdx.x;
    const int row   = bid >> 1;
    const int half  = bid & 1;
    const int batch = row / NFRAMES;
    const int frame = row - batch * NFRAMES;
    const int t0    = frame * PFRAME;
    const int ob    = half * BOUT;
    const int t     = threadIdx.x;

    // ---------------- stage x window + h ----------------
    {
        const float* xb = x + batch * T_TOTAL;
        for (int j = t; j < XWN; j += 256) {
            const int xi = t0 - 2079 + j;
            const float v = (xi >= 0 && xi < T_TOTAL) ? xb[xi] : 0.0f;
            xws[XPHYS(j)] = v;
        }
        const float* hr = hw + row * IR_LEN;
        for (int j = t; j < IR_LEN; j += 256) hh[j] = hr[j];
    }
    __syncthreads();

    // ---------------- FIR: z[o], o in [ob, ob+80) ----------------
    if (t < 250) {
        const int lo0 = (t % 10) * 8;          // local output base 0..72
        const int o0  = ob + lo0;
        const int kc  = t / 10;                // 0..24
        const int kb  = kc * CHL;
        float s0[8] = {0,0,0,0,0,0,0,0};
        int Bo = o0 + 1996 - kb;               // mult of 4, >= 0
        float4 w1 = *(const float4*)&xws[XPHYS(Bo + 4)];
        float4 w2 = *(const float4*)&xws[XPHYS(Bo + 8)];
        for (int s = 0; s < CHL / 4; s++) {    // 20 iters, no tail
            const float4 w0 = *(const float4*)&xws[XPHYS(Bo)];
            const float4 ha = *(const float4*)&hh[kb + 4 * s];
            const float wv[12] = {w0.x, w0.y, w0.z, w0.w,
                                  w1.x, w1.y, w1.z, w1.w,
                                  w2.x, w2.y, w2.z, w2.w};
            const float hav[4] = {ha.x, ha.y, ha.z, ha.w};
            #pragma unroll
            for (int jo = 0; jo < 8; jo++) {
                #pragma unroll
                for (int jk = 0; jk < 4; jk++) {
                    s0[jo] += hav[jk] * wv[3 + jo - jk];
                }
            }
            w2 = w1; w1 = w0; Bo -= 4;
        }
        const int rb = kc * RSTR + lo0;
        *(float4*)&red[rb]     = make_float4(s0[0], s0[1], s0[2], s0[3]);
        *(float4*)&red[rb + 4] = make_float4(s0[4], s0[5], s0[6], s0[7]);
    }
    __syncthreads();

    // ---------------- epilogue: tent-weighted atomic scatter ----------------
    if (t < BOUT) {
        float z = 0.0f;
        #pragma unroll
        for (int kc = 0; kc < NCH; kc++) z += red[kc * RSTR + t];
        const int o = ob + t;
        const int tout = t0 - PFRAME + o;
        float wgt = (o < PFRAME) ? (float)o * (1.0f / PFRAME)
                                 : (float)(160 - o) * (1.0f / PFRAME);
        if (frame == NFRAMES - 1 && o >= PFRAME) wgt = 1.0f;  // clamped h_next
        if (tout >= 0) {                       // frame 0 has no previous frame
            atomicAdd(&y[batch * T_TOTAL + tout], wgt * z);
        }
    }
}

extern "C" void kernel_launch(void* const* d_in, const int* in_sizes, int n_in,
                              void* d_out, int out_size, void* d_ws, size_t ws_size,
                              hipStream_t stream) {
    const float* x  = (const float*)d_in[0];   // (2, 24000)
    const float* mc = (const float*)d_in[1];   // (2, 300, 25)
    float* y  = (float*)d_out;                 // (2, 24000)
    float* hw = (float*)d_ws;                  // 600 x 2000 floats = 4.8 MB

    hipMemsetAsync(y, 0, (size_t)out_size * sizeof(float), stream);
    minphase_h<<<NROWS, 256, 0, stream>>>(mc, hw);
    fir_scatter<<<NROWS * 2, 256, 0, stream>>>(hw, x, y);
}

// Round 7
// 86.302 us; speedup vs baseline: 1.0740x; 1.0740x over previous
//
#include <hip/hip_runtime.h>
#include <math.h>

#define IR_LEN  2000
#define PFRAME  80
#define NFRAMES 300
#define NBATCH  2
#define NROWS   (NBATCH*NFRAMES)     // 600
#define T_TOTAL (NFRAMES*PFRAME)     // 24000
#define NCOEF   25
#define TWO_PI  6.283185307179586f
#define GS      68                   // G row stride in floats
#define XWN     2160                 // logical x-window floats per block
#define XWPAD   2432                 // physical (4-float pad per 32)

#define XPHYS(B) ((B) + (((B) >> 5) << 2))

__device__ __forceinline__ void fsincos(float a, float* s, float* c) {
    *s = __sinf(a); *c = __cosf(a);
}

// ---------------------------------------------------------------------------
// R23 = R17 fused (proven 41.0 us kernel / 87.3 bench; R22 split REVERTED:
// +5 us round-trip, showed FIR is ~free and minphase is the pole) + TWO
// changes targeting the measured no-overlap pathology (wall ~= blocks/CU x
// per-block wall; co-resident blocks in LOCKSTEP contend for the same pipe
// every phase: trans in E, LDS in S1, VALU in FIR):
//   (1) entry STAGGER: co-resident blocks are typically bid, bid+256,
//       bid+512 (round-robin dispatch) -> sleep (bid>>8)*~1.4us so resident
//       blocks run DIFFERENT phases concurrently (complementary pipes).
//   (2) async x-stage (T14): issue x-window global loads to regs at top,
//       ds_write to xws after phase E (latency hidden under E compute).
// Everything else (E Clenshaw, S1, S2, FIR, epilogue) is R17 verbatim.
// ---------------------------------------------------------------------------
__global__ __launch_bounds__(256) void minphase_fir_fused(
        const float* __restrict__ mc, const float* __restrict__ x,
        float* __restrict__ y) {
    __shared__ __align__(16) float U[8704];    // 34.8 KB union
    __shared__ __align__(16) float xws[XWPAD]; // 9.7 KB padded x window
    __shared__ float csh[NCOEF];
    float* const EHr = U;                      // [4096]      (phase E)
    float* const EHi = U + 4096;               // [4096]
    float* const Gr  = U;                      // [rows b<=32] (stages 1/2)
    float* const Gi  = U + 4352;               // [rows b<=32]
    float* const hU  = U;                      // [2000]      (FIR phase)
    float* const red = U + 4224;               // [12 rows, stride 168]

    const int row   = blockIdx.x;
    const int batch = row / NFRAMES;
    const int frame = row - batch * NFRAMES;
    const int t0    = frame * PFRAME;
    const int t     = threadIdx.x;

    if (t < NCOEF) csh[t] = mc[row * NCOEF + t];

    // ---- async x-stage: issue global loads to regs now, LDS-write later --
    float xv[9];
    {
        const float* xb = x + batch * T_TOTAL;
        #pragma unroll
        for (int k = 0; k < 9; k++) {
            const int j  = t + 256 * k;
            const int xi = t0 - 2079 + j;
            xv[k] = (j < XWN && xi >= 0 && xi < T_TOTAL) ? xb[xi] : 0.0f;
        }
    }

    // ---- stagger: desynchronize co-resident blocks (bid, bid+256, +512) --
    {
        const int rph = blockIdx.x >> 8;       // 0,1,2
        if (rph == 1)      asm volatile("s_sleep 32");   // ~2048 cyc
        else if (rph == 2) asm volatile("s_sleep 64");   // ~4096 cyc
    }
    __syncthreads();   // csh visible

    // ---------------- phase E (Clenshaw, conjugate mirror, chained base) --
    {
        float creg[NCOEF];
        #pragma unroll
        for (int k = 0; k < NCOEF; k++) creg[k] = csh[k];

        float bs, bc; fsincos(-(TWO_PI / 4096.0f) * (float)t, &bs, &bc);
        const float SC =  0.923879532511287f;   // cos(pi/8)
        const float SS = -0.382683432365090f;   // sin(-pi/8)
        #pragma unroll 4
        for (int ii = 0; ii < 8; ii++) {
            const int f = t + 256 * ii;                // 0..2047
            const float wc = bc, ws = bs;              // e^{-2pi i f/4096}
            { const float nr = bc * SC - bs * SS;      // advance base
              const float ni = bc * SS + bs * SC;
              bc = nr; bs = ni; }
            const float t2 = 2.0f * wc;
            float b1 = 0.0f, b2 = 0.0f;
            #pragma unroll
            for (int k = NCOEF - 1; k >= 1; k--) {
                const float bk = __fmaf_rn(t2, b1, creg[k] - b2);
                b2 = b1; b1 = bk;
            }
            const float Cr = __fmaf_rn(wc, b1, creg[0] - b2);
            const float Ci = ws * b1;
            const float m = __expf(Cr);
            float si, co; fsincos(Ci, &si, &co);
            const float er = m * co, ei = m * si;
            EHr[f] = er; EHi[f] = ei;
            if (f > 0) { EHr[4096 - f] = er; EHi[4096 - f] = -ei; }
        }
        if (t == 0) {                                  // f = 2048
            float Cr = 0.0f, Ci = 0.0f;
            float cr = 1.0f, ci = 0.0f;
            #pragma unroll
            for (int k = 0; k < NCOEF; k++) {
                Cr += csh[k] * cr; Ci += csh[k] * ci;
                cr = -cr; ci = -ci;                    // e^{-i pi k} = (-1)^k
            }
            const float m = __expf(Cr);
            float si, co; fsincos(Ci, &si, &co);
            EHr[2048] = m * co; EHi[2048] = m * si;
        }
    }

    // ---- x regs -> LDS (global latency was hidden under phase E) --------
    #pragma unroll
    for (int k = 0; k < 9; k++) {
        const int j = t + 256 * k;
        if (j < XWN) xws[XPHYS(j)] = xv[k];
    }
    __syncthreads();

    // ------- stage 1 (R16 shape, wave-contiguous Hermitian tiles) ---------
    {
        const bool act = t < 144;              // waves 0-1 dense, w2 1/4, w3 off
        const int bg = t % 9;                  // b-group 0..8  (b0 = 0..32)
        const int dp = t / 9;                  // d-pair 0..15  (for t < 144)
        const int b0 = bg * 4;
        const int d0 = dp * 2;
        float Ter[2][4], Tei[2][4], Tor[2][4], Toi[2][4];
        #pragma unroll
        for (int j = 0; j < 2; j++)
            #pragma unroll
            for (int i = 0; i < 4; i++) {
                Ter[j][i] = 0.0f; Tei[j][i] = 0.0f;
                Tor[j][i] = 0.0f; Toi[j][i] = 0.0f;
            }
        float rr[2], ri[2], wr[2], wi[2];
        if (act) {
            #pragma unroll
            for (int j = 0; j < 2; j++) {
                float s, c; fsincos((TWO_PI / 32.0f) * (float)(d0 + j), &s, &c);
                wr[j] = c; wi[j] = s; rr[j] = 1.0f; ri[j] = 0.0f;
            }
            // explicit prefetch double-buffer over a2 (R16 verbatim)
            float4 vre = *(const float4*)&EHr[b0];
            float4 vie = *(const float4*)&EHi[b0];
            float4 vro = *(const float4*)&EHr[64 + b0];
            float4 vio = *(const float4*)&EHi[64 + b0];
            #pragma unroll 4
            for (int a2 = 0; a2 < 32; a2++) {
                const float4 cre = vre, cie = vie, cro = vro, cio = vio;
                if (a2 < 31) {
                    const int nb = 128 * (a2 + 1) + b0;
                    vre = *(const float4*)&EHr[nb];
                    vie = *(const float4*)&EHi[nb];
                    vro = *(const float4*)&EHr[nb + 64];
                    vio = *(const float4*)&EHi[nb + 64];
                }
                const float ere[4] = {cre.x, cre.y, cre.z, cre.w};
                const float eie[4] = {cie.x, cie.y, cie.z, cie.w};
                const float ero[4] = {cro.x, cro.y, cro.z, cro.w};
                const float eio[4] = {cio.x, cio.y, cio.z, cio.w};
                #pragma unroll
                for (int j = 0; j < 2; j++) {
                    #pragma unroll
                    for (int i = 0; i < 4; i++) {
                        Ter[j][i] += ere[i] * rr[j] - eie[i] * ri[j];
                        Tei[j][i] += ere[i] * ri[j] + eie[i] * rr[j];
                        Tor[j][i] += ero[i] * rr[j] - eio[i] * ri[j];
                        Toi[j][i] += ero[i] * ri[j] + eio[i] * rr[j];
                    }
                    const float nr = rr[j] * wr[j] - ri[j] * wi[j];
                    const float ni = rr[j] * wi[j] + ri[j] * wr[j];
                    rr[j] = nr; ri[j] = ni;
                }
            }
        }
        __syncthreads();   // uniform barrier: ALL E reads done before G' store

        if (act) {
            // radix-2 butterfly + bd/4096 twiddle + store (b <= 32 only)
            float os[2], oc[2];
            #pragma unroll
            for (int j = 0; j < 2; j++)
                fsincos((TWO_PI / 64.0f) * (float)(d0 + j), &os[j], &oc[j]);
            #pragma unroll
            for (int i = 0; i < 4; i++) {
                const int b = b0 + i;
                if (b > 32) continue;
                float gpr[2], gpi[2], gmr[2], gmi[2];
                #pragma unroll
                for (int j = 0; j < 2; j++) {
                    const int d = d0 + j;
                    const float ur = oc[j] * Tor[j][i] - os[j] * Toi[j][i];
                    const float ui = oc[j] * Toi[j][i] + os[j] * Tor[j][i];
                    const float pr = Ter[j][i] + ur, pi = Tei[j][i] + ui;
                    const float mr = Ter[j][i] - ur, mi = Tei[j][i] - ui;
                    float s, c;
                    fsincos((TWO_PI / 4096.0f) * (float)(b * d), &s, &c);
                    gpr[j] = pr * c - pi * s; gpi[j] = pr * s + pi * c;
                    fsincos((TWO_PI / 4096.0f) * (float)(b * (d + 32)), &s, &c);
                    gmr[j] = mr * c - mi * s; gmi[j] = mr * s + mi * c;
                }
                *(float2*)&Gr[b * GS + d0]      = make_float2(gpr[0], gpr[1]);
                *(float2*)&Gi[b * GS + d0]      = make_float2(gpi[0], gpi[1]);
                *(float2*)&Gr[b * GS + d0 + 32] = make_float2(gmr[0], gmr[1]);
                *(float2*)&Gi[b * GS + d0 + 32] = make_float2(gmi[0], gmi[1]);
            }
        }
    }
    __syncthreads();

    // ---------------- stage 2 (R17 rolled loop, 4 groups = b 0..31) -------
    float hv[4][2];
    int   dl_, cg_;
    {
        const int dl = (t & 31) * 2;
        const int cg = t >> 5;                     // 0..7
        dl_ = dl; cg_ = cg;
        float swi_, swr_; fsincos((TWO_PI / 64.0f) * (float)cg, &swi_, &swr_);
        const float swr = swr_, swi = swi_;        // step e^{2pi i cg/64}
        float rr = 1.0f, ri = 0.0f;
        float acc00 = 0, acc01 = 0, acc10 = 0, acc11 = 0;
        float acc20 = 0, acc21 = 0, acc30 = 0, acc31 = 0;
        int bb = 0;

#define S2C 0.70710678118654752f
#define STEP2(f8r, f8i, f16r, f16i, f24r, f24i)                                \
        {                                                                      \
            const float2 g_r = *(const float2*)&Gr[bb * GS + dl];              \
            const float2 g_i = *(const float2*)&Gi[bb * GS + dl];              \
            acc00 += g_r.x * rr - g_i.x * ri;                                  \
            acc01 += g_r.y * rr - g_i.y * ri;                                  \
            { const float tr = rr*(f8r) - ri*(f8i), ti = rr*(f8i) + ri*(f8r);  \
              acc10 += g_r.x * tr - g_i.x * ti;                                \
              acc11 += g_r.y * tr - g_i.y * ti; }                              \
            { const float tr = rr*(f16r) - ri*(f16i), ti = rr*(f16i) + ri*(f16r); \
              acc20 += g_r.x * tr - g_i.x * ti;                                \
              acc21 += g_r.y * tr - g_i.y * ti; }                              \
            { const float tr = rr*(f24r) - ri*(f24i), ti = rr*(f24i) + ri*(f24r); \
              acc30 += g_r.x * tr - g_i.x * ti;                                \
              acc31 += g_r.y * tr - g_i.y * ti; }                              \
            { const float nr = rr * swr - ri * swi;                            \
              const float ni = rr * swi + ri * swr;                            \
              rr = nr; ri = ni; }                                              \
            bb++;                                                              \
        }

        #pragma unroll 1
        for (int grp = 0; grp < 4; grp++) {        // b = 0..31 (rolled!)
            STEP2( 1.0f, 0.0f,   1.0f, 0.0f,   1.0f, 0.0f)
            STEP2( S2C,  S2C,    0.0f, 1.0f,  -S2C,  S2C)
            STEP2( 0.0f, 1.0f,  -1.0f, 0.0f,   0.0f,-1.0f)
            STEP2(-S2C,  S2C,    0.0f,-1.0f,   S2C,  S2C)
            STEP2(-1.0f, 0.0f,   1.0f, 0.0f,  -1.0f, 0.0f)
            STEP2(-S2C, -S2C,    0.0f, 1.0f,   S2C, -S2C)
            STEP2( 0.0f,-1.0f,  -1.0f, 0.0f,   0.0f, 1.0f)
            STEP2( S2C, -S2C,    0.0f,-1.0f,  -S2C, -S2C)
        }
#undef STEP2

        // Hermitian fixup: true sum = 2*acc - g0 + (-1)^cg * g32, /4096
        const float g0a  = Gr[dl],           g0b  = Gr[dl + 1];
        const float g32a = Gr[32 * GS + dl], g32b = Gr[32 * GS + dl + 1];
        const float sgn  = (cg & 1) ? -1.0f : 1.0f;   // (-1)^{cg+8v} = (-1)^cg
        const float sc = 1.0f / 4096.0f;
        hv[0][0] = (2.0f * acc00 - g0a + sgn * g32a) * sc;
        hv[0][1] = (2.0f * acc01 - g0b + sgn * g32b) * sc;
        hv[1][0] = (2.0f * acc10 - g0a + sgn * g32a) * sc;
        hv[1][1] = (2.0f * acc11 - g0b + sgn * g32b) * sc;
        hv[2][0] = (2.0f * acc20 - g0a + sgn * g32a) * sc;
        hv[2][1] = (2.0f * acc21 - g0b + sgn * g32b) * sc;
        hv[3][0] = (2.0f * acc30 - g0a + sgn * g32a) * sc;
        hv[3][1] = (2.0f * acc31 - g0b + sgn * g32b) * sc;
    }
    __syncthreads();   // all G reads done; U is free

    // ---------------- h -> LDS ----------------
    #pragma unroll
    for (int v = 0; v < 4; v++) {
        const int c = cg_ + 8 * v;
        const int n = 64 * c + dl_;
        if (n < IR_LEN)     hU[n]     = hv[v][0];
        if (n + 1 < IR_LEN) hU[n + 1] = hv[v][1];
    }
    __syncthreads();

    // ---------------- FIR: z[o], o in [0,160) ----------------
    if (t < 240) {
        const int o0 = (t % 20) * 8;
        const int kc = t / 20;                 // 0..11
        const int kb = kc * 168;
        const int ns = (kc == 11) ? 38 : 42;   // 11*168=1848, +152 = 2000
        float s0[8] = {0,0,0,0,0,0,0,0};
        int Bo = o0 + 1996 - kb;               // mult of 4, >= 0
        float4 w1 = *(const float4*)&xws[XPHYS(Bo + 4)];
        float4 w2 = *(const float4*)&xws[XPHYS(Bo + 8)];
        for (int s = 0; s < ns; s++) {
            const float4 w0 = *(const float4*)&xws[XPHYS(Bo)];
            const float4 ha = *(const float4*)&hU[kb + 4 * s];
            const float wv[12] = {w0.x, w0.y, w0.z, w0.w,
                                  w1.x, w1.y, w1.z, w1.w,
                                  w2.x, w2.y, w2.z, w2.w};
            const float hav[4] = {ha.x, ha.y, ha.z, ha.w};
            #pragma unroll
            for (int jo = 0; jo < 8; jo++) {
                #pragma unroll
                for (int jk = 0; jk < 4; jk++) {
                    s0[jo] += hav[jk] * wv[3 + jo - jk];
                }
            }
            w2 = w1; w1 = w0; Bo -= 4;
        }
        const int rb = kc * 168 + o0;
        *(float4*)&red[rb]     = make_float4(s0[0], s0[1], s0[2], s0[3]);
        *(float4*)&red[rb + 4] = make_float4(s0[4], s0[5], s0[6], s0[7]);
    }
    __syncthreads();

    // ---------------- epilogue: tent-weighted atomic scatter ----------------
    if (t < 160) {
        float z = 0.0f;
        #pragma unroll
        for (int kc = 0; kc < 12; kc++) z += red[kc * 168 + t];
        const int o = t;
        const int tout = t0 - PFRAME + o;
        float wgt = (o < PFRAME) ? (float)o * (1.0f / PFRAME)
                                 : (float)(160 - o) * (1.0f / PFRAME);
        if (frame == NFRAMES - 1 && o >= PFRAME) wgt = 1.0f;  // clamped h_next
        if (tout >= 0) {                       // frame 0 has no previous frame
            atomicAdd(&y[batch * T_TOTAL + tout], wgt * z);
        }
    }
}

extern "C" void kernel_launch(void* const* d_in, const int* in_sizes, int n_in,
                              void* d_out, int out_size, void* d_ws, size_t ws_size,
                              hipStream_t stream) {
    const float* x  = (const float*)d_in[0];   // (2, 24000)
    const float* mc = (const float*)d_in[1];   // (2, 300, 25)
    float* y = (float*)d_out;                  // (2, 24000)

    hipMemsetAsync(y, 0, (size_t)out_size * sizeof(float), stream);
    minphase_fir_fused<<<NROWS, 256, 0, stream>>>(mc, x, y);
}